// Round 1
// 605.501 us; speedup vs baseline: 1.2385x; 1.2385x over previous
//
#include <hip/hip_runtime.h>

// BiLSTM: B=256, T=512, N=128, H=128. fp32 in/out, bf16 MFMA internally.
// Fused: z = [x_t | h] @ [W;U] + b computed per step (no XW intermediate).
//
// This version: 128 blocks = 2 dirs x 64 batch-blocks of FOUR rows each.
// The 4 real batch rows are mapped to MFMA tile rows {0,4,8,12}, so every
// lane's acc[g][0] (C row = quad*4 + 0) is a real element -> activation
// (transcendental) work per thread drops 4x vs the 16-row version, and the
// serial recurrence spreads over 4x more CUs. Tile rows r%4!=0 are padding:
// their [x|h] LDS rows are zeroed once and never written (z = bias, finite,
// and MFMA C-row r depends only on A-row r, so garbage never contaminates
// real rows).
//
// ws layout:
//   [0, 512KB): combined WU bf16 MFMA B-fragments
//               [dir(2)][gate(4)][kc(8)][tile(8)][lane(64)][8]
//               kc<4 -> W rows kc*32.., kc>=4 -> U rows (kc-4)*32..

typedef short s16x8 __attribute__((ext_vector_type(8)));
typedef float f32x4 __attribute__((ext_vector_type(4)));

#define NT 512
#define LDSROW 272   // bf16 per LDS row: 256 data + 16 pad (136 dwords = 8 mod 32 banks)

// Barrier with LDS-only drain (no vmcnt(0) at source level): out-stores and
// the x prefetch stay in flight; data deps get compiler-inserted vmcnt(N).
#define LDS_BARRIER() asm volatile("s_waitcnt lgkmcnt(0)\n\ts_barrier" ::: "memory")

__device__ __forceinline__ unsigned short f2bf(float f) {
  unsigned int u = __float_as_uint(f);
  u += 0x7fffu + ((u >> 16) & 1u);   // RNE
  return (unsigned short)(u >> 16);
}
__device__ __forceinline__ float sigm(float x) {
  return __builtin_amdgcn_rcpf(1.f + __expf(-x));      // 2 trans, no div-fixup
}
__device__ __forceinline__ float tanh_(float x) {
  float xc = fminf(fmaxf(x, -12.f), 12.f);
  return 1.f - 2.f * __builtin_amdgcn_rcpf(1.f + __expf(2.f * xc));
}

// ---------------------------------------------------------------- kernel 0
// Repack [W;U] (fp32 [128][512] each) into bf16 B-fragment order, K=256.
// B-frag (16x16x32): lane holds B[k = (lane>>4)*8 + j][n = lane&15].
__global__ void prep_frags(const float* __restrict__ Wf, const float* __restrict__ Uf,
                           const float* __restrict__ Wb, const float* __restrict__ Ub,
                           unsigned short* __restrict__ frag) {
  int idx = blockIdx.x * 256 + threadIdx.x;          // 0 .. 2^18-1
  int j    = idx & 7;
  int lane = (idx >> 3) & 63;
  int tile = (idx >> 9) & 7;
  int kc   = (idx >> 12) & 7;
  int gate = (idx >> 15) & 3;
  int dir  = (idx >> 17) & 1;
  const float* M = (kc < 4) ? (dir ? Wb : Wf) : (dir ? Ub : Uf);
  int k   = (kc & 3) * 32 + (lane >> 4) * 8 + j;
  int col = gate * 128 + tile * 16 + (lane & 15);
  frag[idx] = f2bf(M[k * 512 + col]);
}

// ---------------------------------------------------------------- kernel 1
// Persistent fused recurrent kernel. 128 blocks = 2 dirs x 64 batch-blocks
// (4 real rows each, mapped to tile rows 0,4,8,12). 8 waves; wave = column-
// slice tc (16 cols x all 4 gates), so i,f,g,o stay in-register. One LDS
// barrier per step, double-buffered [x_t | h] tile in LDS, WU fragments in
// registers (128 VGPRs).
__global__ __launch_bounds__(512, 2) void bilstm_rec(
    const unsigned short* __restrict__ frag, const float* __restrict__ x,
    const float* __restrict__ bfw, const float* __restrict__ bbw,
    float* __restrict__ out) {
  __shared__ unsigned short xh[2][16][LDSROW];   // cols 0..127 = x_t, 128..255 = h

  int bid = blockIdx.x;
  int bblk = bid & 63, dir = bid >> 6;
  int tid = threadIdx.x;
  int tc = tid >> 6, lane = tid & 63, quad = lane >> 4, m = lane & 15;

  // WU fragments for (dir, all gates, tile tc): 32 frags -> 128 VGPRs
  s16x8 wu[4][8];   // [gate][kc]
#pragma unroll
  for (int g = 0; g < 4; g++)
#pragma unroll
    for (int kc = 0; kc < 8; kc++)
      wu[g][kc] = *(const s16x8*)(frag +
          ((((size_t)(dir * 4 + g) * 8 + kc) * 8 + tc) * 64 + lane) * 8);

  const float* bias = dir ? bbw : bfw;
  float bv[4];
#pragma unroll
  for (int g = 0; g < 4; g++) bv[g] = bias[g * 128 + tc * 16 + m];

  // x staging ownership: thread -> (real row srow in 0..3, 1 col)
  int srow = tid >> 7, scol = tid & 127;
  const float* xbase = x + ((size_t)(bblk * 4 + srow) * NT) * 128 + scol;

  // zero ALL of LDS (padding rows must read as 0 forever; h starts at 0)
  {
    unsigned int* zp = (unsigned int*)&xh[0][0][0];
    for (int i = tid; i < 2 * 16 * (LDSROW / 2); i += 512) zp[i] = 0;
  }
  __syncthreads();

  // prologue: stage x(t_in(0)) into xh[0] rows {0,4,8,12}
  {
    int t0 = dir ? (NT - 1) : 0;
    xh[0][srow * 4][scol] = f2bf(xbase[(size_t)t0 * 128]);
  }
  __syncthreads();

  float cc = 0.f;   // cell state for (batch row quad, col tc*16+m)
  float* outp = out + (size_t)(bblk * 4 + quad) * (NT * 256) + dir * 128 + tc * 16 + m;

  for (int s = 0; s < NT; s++) {
    int cb = s & 1, nb = cb ^ 1;

    // x prefetch for step s+1 (issued first: latency overlaps whole body)
    int sn = (s + 1 < NT) ? (s + 1) : (NT - 1);
    int tn = dir ? (NT - 1 - sn) : sn;
    float vx = xbase[(size_t)tn * 128];

    // A-frags [x_t | h] from LDS buffer cb (bank-balanced ds_read_b128 x8)
    s16x8 a[8];
#pragma unroll
    for (int kc = 0; kc < 8; kc++)
      a[kc] = *(const s16x8*)(&xh[cb][m][kc * 32 + quad * 8]);

    f32x4 acc[4];
#pragma unroll
    for (int g = 0; g < 4; g++) {
      acc[g][0] = bv[g]; acc[g][1] = bv[g]; acc[g][2] = bv[g]; acc[g][3] = bv[g];
    }
#pragma unroll
    for (int kc = 0; kc < 8; kc++)
#pragma unroll
      for (int g = 0; g < 4; g++)
        acc[g] = __builtin_amdgcn_mfma_f32_16x16x32_bf16(a[kc], wu[g][kc], acc[g], 0, 0, 0);

    // activations only on the real element: C row quad*4 (reg 0), col tc*16+m
    float iv = sigm(acc[0][0]);
    float fv = sigm(acc[1][0]);
    float gv = tanh_(acc[2][0]);
    float ov = sigm(acc[3][0]);
    cc = fv * cc + iv * gv;
    float hv = ov * tanh_(cc);

    // LDS writes first (they gate the barrier's lgkmcnt drain)
    xh[nb][quad * 4][128 + tc * 16 + m] = f2bf(hv);
    xh[nb][srow * 4][scol] = f2bf(vx);

    // global out store last (can stay in flight across the barrier)
    outp[(size_t)s * 256] = hv;

    LDS_BARRIER();
  }
}

extern "C" void kernel_launch(void* const* d_in, const int* in_sizes, int n_in,
                              void* d_out, int out_size, void* d_ws, size_t ws_size,
                              hipStream_t stream) {
  const float* x  = (const float*)d_in[0];
  const float* Wf = (const float*)d_in[1];
  const float* Uf = (const float*)d_in[2];
  const float* bf = (const float*)d_in[3];
  const float* Wb = (const float*)d_in[4];
  const float* Ub = (const float*)d_in[5];
  const float* bb = (const float*)d_in[6];
  float* out = (float*)d_out;

  unsigned short* frag = (unsigned short*)d_ws;

  prep_frags<<<1024, 256, 0, stream>>>(Wf, Uf, Wb, Ub, frag);
  bilstm_rec<<<128, 512, 0, stream>>>(frag, x, bf, bb, out);
}